// Round 2
// baseline (144.026 us; speedup 1.0000x reference)
//
#include <hip/hip_runtime.h>
#include <math.h>

#define D 64
#define C 22
#define NCHUNK 16
#define CHUNK 1024          // covers Nt=16384 exactly; INF-padded otherwise
#define SPT 2               // students per thread in nn_kernel
#define TEMP_F 2.0f
#define KL_W_F 0.2f

// ---------------------------------------------------------------- 1-NN (chunked, 2 students/thread)
// LDS holds (-2x, -2y, -2z, |t|^2) so each distance is a pure 3-FMA chain:
//   val = fma(sx,-2tx, fma(sy,-2ty, fma(sz,-2tz, t2)))  ==  |t|^2 - 2 s.t
// (|s|^2 dropped: constant per student, preserves argmin)
__global__ void __launch_bounds__(256) nn_kernel(
                          const float* __restrict__ sc,   // [Ns][3]
                          const float* __restrict__ tc,   // [Nt][3]
                          float* __restrict__ cand_d2,    // [Ns][NCHUNK]
                          int*   __restrict__ cand_idx,   // [Ns][NCHUNK]
                          int Ns, int Nt)
{
    __shared__ float4 tl[CHUNK];
    const int chunk = blockIdx.y;
    const int base  = chunk * CHUNK;

    for (int j = threadIdx.x; j < CHUNK; j += blockDim.x) {
        int g = base + j;
        if (g < Nt) {
            float x = tc[(size_t)g * 3 + 0];
            float y = tc[(size_t)g * 3 + 1];
            float z = tc[(size_t)g * 3 + 2];
            tl[j] = make_float4(-2.0f * x, -2.0f * y, -2.0f * z, x * x + y * y + z * z);
        } else {
            tl[j] = make_float4(0.f, 0.f, 0.f, INFINITY);
        }
    }
    __syncthreads();

    const int i0 = blockIdx.x * (blockDim.x * SPT) + threadIdx.x;
    const int i1 = i0 + blockDim.x;

    float sx0 = 0.f, sy0 = 0.f, sz0 = 0.f;
    float sx1 = 0.f, sy1 = 0.f, sz1 = 0.f;
    if (i0 < Ns) {
        sx0 = sc[(size_t)i0 * 3 + 0];
        sy0 = sc[(size_t)i0 * 3 + 1];
        sz0 = sc[(size_t)i0 * 3 + 2];
    }
    if (i1 < Ns) {
        sx1 = sc[(size_t)i1 * 3 + 0];
        sy1 = sc[(size_t)i1 * 3 + 1];
        sz1 = sc[(size_t)i1 * 3 + 2];
    }

    float best0 = INFINITY, best1 = INFINITY;
    int   b0 = base, b1 = base;

#pragma unroll 8
    for (int j = 0; j < CHUNK; ++j) {
        float4 t = tl[j];
        float v0 = fmaf(sx0, t.x, fmaf(sy0, t.y, fmaf(sz0, t.z, t.w)));
        float v1 = fmaf(sx1, t.x, fmaf(sy1, t.y, fmaf(sz1, t.z, t.w)));
        int jj = base + j;
        bool c0 = v0 < best0;                       // strict <: keep first min
        bool c1 = v1 < best1;
        best0 = c0 ? v0 : best0;  b0 = c0 ? jj : b0;
        best1 = c1 ? v1 : best1;  b1 = c1 ? jj : b1;
    }

    if (i0 < Ns) {
        cand_d2 [(size_t)i0 * NCHUNK + chunk] = best0;
        cand_idx[(size_t)i0 * NCHUNK + chunk] = b0;
    }
    if (i1 < Ns) {
        cand_d2 [(size_t)i1 * NCHUNK + chunk] = best1;
        cand_idx[(size_t)i1 * NCHUNK + chunk] = b1;
    }
}

// ---------------------------------------------------------------- fused loss
// Reduces NN candidates, gathers matched teacher FEATURES, computes both the
// teacher and student 22-way logits in-register, then CE + KL contributions.
__global__ void loss_kernel(const float* __restrict__ s_feat,   // [Ns][D]
                            const float* __restrict__ t_feat,   // [Nt][D]
                            const float* __restrict__ Ws,       // [C][D]
                            const float* __restrict__ bs_,      // [C]
                            const float* __restrict__ Wt,       // [C][D]
                            const float* __restrict__ bt_,      // [C]
                            const int*   __restrict__ segment,  // [Ns]
                            const float* __restrict__ cand_d2,
                            const int*   __restrict__ cand_idx,
                            float* __restrict__ acc,            // [0]=seg_sum [1]=kl_sum
                            int Ns)
{
    __shared__ __align__(16) float ws[C * D];
    __shared__ __align__(16) float wt[C * D];
    __shared__ float bsh[C], bth[C];
    __shared__ float red_seg[8], red_kl[8];

    for (int k = threadIdx.x; k < C * D; k += blockDim.x) { ws[k] = Ws[k]; wt[k] = Wt[k]; }
    if (threadIdx.x < C) { bsh[threadIdx.x] = bs_[threadIdx.x]; bth[threadIdx.x] = bt_[threadIdx.x]; }
    __syncthreads();

    int i = blockIdx.x * blockDim.x + threadIdx.x;
    float seg_i = 0.f, kl_i = 0.f;

    if (i < Ns) {
        // reduce NN candidates (chunk-ascending, strict < keeps first occurrence)
        float best = cand_d2[(size_t)i * NCHUNK];
        int   bidx = cand_idx[(size_t)i * NCHUNK];
#pragma unroll
        for (int k = 1; k < NCHUNK; ++k) {
            float v = cand_d2[(size_t)i * NCHUNK + k];
            int   x = cand_idx[(size_t)i * NCHUNK + k];
            if (v < best) { best = v; bidx = x; }
        }

        // ---- teacher logits from gathered teacher features
        float t[C];
        {
            float4 g[D / 4];
            const float4* gr = reinterpret_cast<const float4*>(t_feat + (size_t)bidx * D);
#pragma unroll
            for (int k = 0; k < D / 4; ++k) g[k] = gr[k];
#pragma unroll
            for (int c = 0; c < C; ++c) {
                float a = bth[c];
                const float4* wr = reinterpret_cast<const float4*>(&wt[c * D]);
#pragma unroll
                for (int k = 0; k < D / 4; ++k) {
                    float4 wv = wr[k];
                    a = fmaf(g[k].x, wv.x, a);
                    a = fmaf(g[k].y, wv.y, a);
                    a = fmaf(g[k].z, wv.z, a);
                    a = fmaf(g[k].w, wv.w, a);
                }
                t[c] = a;
            }
        }

        // ---- student logits
        float l[C];
        {
            float4 f[D / 4];
            const float4* fr = reinterpret_cast<const float4*>(s_feat + (size_t)i * D);
#pragma unroll
            for (int k = 0; k < D / 4; ++k) f[k] = fr[k];
#pragma unroll
            for (int c = 0; c < C; ++c) {
                float a = bsh[c];
                const float4* wr = reinterpret_cast<const float4*>(&ws[c * D]);
#pragma unroll
                for (int k = 0; k < D / 4; ++k) {
                    float4 wv = wr[k];
                    a = fmaf(f[k].x, wv.x, a);
                    a = fmaf(f[k].y, wv.y, a);
                    a = fmaf(f[k].z, wv.z, a);
                    a = fmaf(f[k].w, wv.w, a);
                }
                l[c] = a;
            }
        }

        // ---- student softmax stats (T=1 for CE, T=2 for KL)
        float m1 = l[0];
#pragma unroll
        for (int c = 1; c < C; ++c) m1 = fmaxf(m1, l[c]);
        float sum1 = 0.f, sum2 = 0.f;
#pragma unroll
        for (int c = 0; c < C; ++c) {
            float d = l[c] - m1;
            sum1 += expf(d);
            sum2 += expf(0.5f * d);
        }
        float lse1 = logf(sum1);
        float lse2 = logf(sum2);

        int sg = segment[i];
        seg_i = -(l[sg] - m1 - lse1);

        // ---- teacher softmax (T=2) + KL
        float mt = t[0];
#pragma unroll
        for (int c = 1; c < C; ++c) mt = fmaxf(mt, t[c]);
        float den = 0.f;
        float e[C];
#pragma unroll
        for (int c = 0; c < C; ++c) {
            e[c] = expf(0.5f * (t[c] - mt));
            den += e[c];
        }
        float logden = logf(den);
        float inv = 1.0f / den;

        float kls = 0.f;
#pragma unroll
        for (int c = 0; c < C; ++c) {
            float logtp = 0.5f * (t[c] - mt) - logden;   // log teacher_p
            float slp   = 0.5f * (l[c] - m1) - lse2;     // student log-softmax (T=2)
            kls = fmaf(e[c] * inv, logtp - slp, kls);
        }
        kl_i = kls;
    }

    // wave64 shuffle reduce, cross-wave via LDS, one atomic pair per block
#pragma unroll
    for (int off = 32; off > 0; off >>= 1) {
        seg_i += __shfl_down(seg_i, off);
        kl_i  += __shfl_down(kl_i,  off);
    }
    int lane = threadIdx.x & 63;
    int wv   = threadIdx.x >> 6;
    if (lane == 0) { red_seg[wv] = seg_i; red_kl[wv] = kl_i; }
    __syncthreads();
    if (threadIdx.x == 0) {
        int nw = (blockDim.x + 63) >> 6;
        float s = 0.f, k = 0.f;
        for (int w = 0; w < nw; ++w) { s += red_seg[w]; k += red_kl[w]; }
        atomicAdd(&acc[0], s);
        atomicAdd(&acc[1], k);
    }
}

// ---------------------------------------------------------------- finalize
__global__ void finalize_kernel(const float* __restrict__ acc, float* __restrict__ out, int Ns)
{
    float seg_loss = acc[0] / (float)Ns;
    float kl_loss  = KL_W_F * (acc[1] / (float)Ns) * TEMP_F * TEMP_F;
    out[0] = seg_loss + kl_loss;
    out[1] = seg_loss;
    out[2] = kl_loss;
}

extern "C" void kernel_launch(void* const* d_in, const int* in_sizes, int n_in,
                              void* d_out, int out_size, void* d_ws, size_t ws_size,
                              hipStream_t stream)
{
    const float* s_feat  = (const float*)d_in[0];
    const float* t_feat  = (const float*)d_in[1];
    const float* s_coord = (const float*)d_in[2];
    const float* t_coord = (const float*)d_in[3];
    const float* seg_W   = (const float*)d_in[4];
    const float* seg_b   = (const float*)d_in[5];
    const float* seg_tW  = (const float*)d_in[6];
    const float* seg_tb  = (const float*)d_in[7];
    const int*   segment = (const int*)d_in[8];
    float* out = (float*)d_out;

    const int Ns = in_sizes[0] / D;
    const int Nt = in_sizes[1] / D;

    float* cand_d2 = (float*)d_ws;                           // [Ns*NCHUNK]
    int*   cand_ix = (int*)(cand_d2 + (size_t)Ns * NCHUNK);  // [Ns*NCHUNK]
    float* acc     = (float*)(cand_ix + (size_t)Ns * NCHUNK);

    hipMemsetAsync(acc, 0, 2 * sizeof(float), stream);

    // nn: 2 students/thread, 256 threads -> 512 students per block
    int nn_bx = (Ns + 256 * SPT - 1) / (256 * SPT);
    nn_kernel<<<dim3(nn_bx, NCHUNK), 256, 0, stream>>>(s_coord, t_coord,
                                                       cand_d2, cand_ix, Ns, Nt);

    // fused loss: 128 threads -> 128 blocks at Ns=16384 (spreads over more CUs)
    int ls_b = (Ns + 127) / 128;
    loss_kernel<<<ls_b, 128, 0, stream>>>(s_feat, t_feat, seg_W, seg_b, seg_tW, seg_tb,
                                          segment, cand_d2, cand_ix, acc, Ns);
    finalize_kernel<<<1, 1, 0, stream>>>(acc, out, Ns);
}